// Round 11
// baseline (186.888 us; speedup 1.0000x reference)
//
#include <hip/hip_runtime.h>

#define SEQ   2048
#define BATCH 32
#define INF   256
#define NST   512
#define OUTF  256
#define CLEN  32
#define NCH   64
#define NJOB  4
#define NCG   (NCH / NJOB)          /* 16 chunk-groups of 128 timesteps */
#define NBLK  (NCG * BATCH)         /* 512 blocks */

typedef __bf16 bf16;
typedef __bf16 bf16x8 __attribute__((ext_vector_type(8)));
typedef float  f32x4  __attribute__((ext_vector_type(4)));

// ---------------------------------------------------------------------------
// K1: lam=exp(-exp(ll)); lamG=lam^128; l2la=log2(lam); B'=gamma*B bf16; C bf16
// ---------------------------------------------------------------------------
__global__ void k_prep(const float* __restrict__ ll,
                       const float* __restrict__ Bm,
                       const float* __restrict__ Cm,
                       float* __restrict__ lam,
                       float* __restrict__ lamG,
                       float* __restrict__ l2la,
                       bf16* __restrict__ Bb,
                       bf16* __restrict__ Cb) {
  int i = blockIdx.x * 256 + threadIdx.x;
  if (i < NST) {
    float e = expf(ll[i]);          // -ln(lambda)
    float lmb = expf(-e);
    lam[i] = lmb;
    l2la[i] = -e * 1.44269504088896341f;   // log2(lambda)
    float p = lmb;
#pragma unroll
    for (int q = 0; q < 7; ++q) p *= p;    // lambda^128
    lamG[i] = p;
  }
  if (i < NST * INF) {
    int n = i >> 8;
    float lmb = expf(-expf(ll[n]));
    float g = sqrtf(1.0f - lmb * lmb + 1e-7f);
    Bb[i] = (bf16)(Bm[i] * g);
  }
  if (i < OUTF * NST) {
    Cb[i] = (bf16)(Cm[i]);
  }
}

// ---------------------------------------------------------------------------
// x staging helpers. LDS layout: [t][i] bf16, byte = (t*512+i*2) ^ ((t&15)<<4)
// ---------------------------------------------------------------------------
__device__ __forceinline__ void xload(const float* __restrict__ xp, int tid,
                                      float4 xr[4]) {
#pragma unroll
  for (int rep = 0; rep < 4; ++rep) {
    int slot = rep * 512 + tid;
    int row = slot >> 6, col4 = slot & 63;
    xr[rep] = *(const float4*)(xp + (size_t)row * (BATCH * INF) + col4 * 4);
  }
}

__device__ __forceinline__ void xstore(char* xsb, int tid, const float4 xr[4]) {
#pragma unroll
  for (int rep = 0; rep < 4; ++rep) {
    int slot = rep * 512 + tid;
    int row = slot >> 6, col4 = slot & 63;
    union { bf16 h[4]; unsigned long long u; } pk;
    pk.h[0] = (bf16)xr[rep].x; pk.h[1] = (bf16)xr[rep].y;
    pk.h[2] = (bf16)xr[rep].z; pk.h[3] = (bf16)xr[rep].w;
    int byte = (row * (INF * 2) + col4 * 8) ^ ((row & 15) << 4);
    *(unsigned long long*)(xsb + byte) = pk.u;
  }
}

// ---------------------------------------------------------------------------
// OLD-orientation in-register scan (fallback path): lane holds 4 t at fixed n.
// ---------------------------------------------------------------------------
__device__ __forceinline__ void reg_scan(f32x4 acc[2][4], float carry[4],
                                         const float la[4], const float l4[4],
                                         int kg, int rl) {
#pragma unroll
  for (int mt = 0; mt < 2; ++mt) {
    float sl[4][4];
#pragma unroll
    for (int nt = 0; nt < 4; ++nt) {
      sl[nt][0] = acc[mt][nt][0];
      sl[nt][1] = fmaf(la[nt], sl[nt][0], acc[mt][nt][1]);
      sl[nt][2] = fmaf(la[nt], sl[nt][1], acc[mt][nt][2]);
      sl[nt][3] = fmaf(la[nt], sl[nt][2], acc[mt][nt][3]);
    }
    float G[4];
#pragma unroll
    for (int nt = 0; nt < 4; ++nt) {
      float g1 = __shfl_up(sl[nt][3], 16);
      G[nt] = (kg >= 1) ? fmaf(l4[nt], g1, sl[nt][3]) : sl[nt][3];
    }
#pragma unroll
    for (int nt = 0; nt < 4; ++nt) {
      float l8 = l4[nt] * l4[nt];
      float g2 = __shfl_up(G[nt], 32);
      G[nt] = (kg >= 2) ? fmaf(l8, g2, G[nt]) : G[nt];
    }
#pragma unroll
    for (int nt = 0; nt < 4; ++nt) {
      float X = __shfl_up(G[nt], 16);
      X = (kg >= 1) ? X : 0.0f;
      float l8 = l4[nt] * l4[nt];
      float p4k = ((kg & 1) ? l4[nt] : 1.0f) * ((kg & 2) ? l8 : 1.0f);
      float cin = fmaf(p4k, carry[nt], X);
      float l2 = la[nt] * la[nt], l3 = l2 * la[nt];
      acc[mt][nt][0] = fmaf(la[nt], cin, sl[nt][0]);
      acc[mt][nt][1] = fmaf(l2, cin, sl[nt][1]);
      acc[mt][nt][2] = fmaf(l3, cin, sl[nt][2]);
      acc[mt][nt][3] = fmaf(l4[nt], cin, sl[nt][3]);
    }
#pragma unroll
    for (int nt = 0; nt < 4; ++nt)
      carry[nt] = __shfl(acc[mt][nt][3], rl + 48);
  }
}

// ---------------------------------------------------------------------------
// GEMM1 fragment loaders (shared by both orientations)
// ---------------------------------------------------------------------------
__device__ __forceinline__ void gemm1_l2(const char* xsb, const bf16* __restrict__ Bb,
                                         f32x4 acc[2][4], int n0, int rl, int kg) {
#pragma unroll
  for (int k = 0; k < 8; ++k) {
    bf16x8 af[2], bfr[4];
#pragma unroll
    for (int mt = 0; mt < 2; ++mt) {
      int row = mt * 16 + rl;
      int byte = (row * (INF * 2) + (k * 32 + kg * 8) * 2) ^ (rl << 4);
      af[mt] = *(const bf16x8*)(xsb + byte);
    }
#pragma unroll
    for (int nt = 0; nt < 4; ++nt)
      bfr[nt] = *(const bf16x8*)(Bb + (size_t)(n0 + nt * 16 + rl) * INF + k * 32 + kg * 8);
#pragma unroll
    for (int mt = 0; mt < 2; ++mt)
#pragma unroll
      for (int nt = 0; nt < 4; ++nt)
        acc[mt][nt] = __builtin_amdgcn_mfma_f32_16x16x32_bf16(af[mt], bfr[nt], acc[mt][nt], 0, 0, 0);
  }
}

// ---------------------------------------------------------------------------
// PASS0S: swapped-operand GEMM1 (D = B'*x^T -> [n][t]); lane-transposed scan;
// 8B packed bfrag stores; float4 Z store. B' in regs. Persistent (b,cg) x4 jobs.
// bfrag layout: [(cg*32+b)*128 + dt][n]  (identical to R10)
// ---------------------------------------------------------------------------
__global__ __launch_bounds__(512)
void k_pass0s(const float* __restrict__ x, const bf16* __restrict__ Bb,
              const float* __restrict__ lam, float* __restrict__ Z,
              bf16* __restrict__ bfrag) {
  __shared__ __align__(16) char xs[2][CLEN * INF * 2];   // 2x16KB

  const int tid = threadIdx.x, wid = tid >> 6, lane = tid & 63;
  const int rl = lane & 15, kg = lane >> 4;
  const int b = blockIdx.x >> 4, cg = blockIdx.x & 15;
  const int n0 = wid * 64;
  const int seg15 = (lane & 48) | 15;    // lane holding t=15 of this segment

  // per-lane lambda for its 4 n (n = n0 + nt*16 + kg*4 + r) and carries
  float la2[4][4], carry2[4][4];
#pragma unroll
  for (int nt = 0; nt < 4; ++nt)
#pragma unroll
    for (int r = 0; r < 4; ++r) {
      la2[nt][r] = lam[n0 + nt * 16 + kg * 4 + r];
      carry2[nt][r] = 0.0f;
    }

  // B' panel in registers (A-operand: lane rl holds row n0+nt*16+rl, k=kg*8..)
  bf16x8 Breg[8][4];
#pragma unroll
  for (int k = 0; k < 8; ++k)
#pragma unroll
    for (int nt = 0; nt < 4; ++nt)
      Breg[k][nt] = *(const bf16x8*)(Bb + (size_t)(n0 + nt * 16 + rl) * INF + k * 32 + kg * 8);

  {
    float4 xr0[4];
    xload(x + ((size_t)(cg * NJOB * CLEN) * BATCH + b) * INF, tid, xr0);
    xstore(xs[0], tid, xr0);
  }
  __syncthreads();

#pragma unroll
  for (int jj = 0; jj < NJOB; ++jj) {
    const int c = cg * NJOB + jj;

    // ---- GEMM1 swapped: acc[mt][nt] holds D[n][t]: t = mt*16+rl, n = kg*4+r
    f32x4 acc[2][4] = {};
#pragma unroll
    for (int k = 0; k < 8; ++k) {
      bf16x8 af[2];
#pragma unroll
      for (int mt = 0; mt < 2; ++mt) {
        int row = mt * 16 + rl;
        int byte = (row * (INF * 2) + (k * 32 + kg * 8) * 2) ^ (rl << 4);
        af[mt] = *(const bf16x8*)(&xs[jj & 1][0] + byte);
      }
#pragma unroll
      for (int mt = 0; mt < 2; ++mt)
#pragma unroll
        for (int nt = 0; nt < 4; ++nt)
          acc[mt][nt] = __builtin_amdgcn_mfma_f32_16x16x32_bf16(Breg[k][nt], af[mt], acc[mt][nt], 0, 0, 0);
    }

    float4 xr[4];
    if (jj < NJOB - 1)
      xload(x + ((size_t)((c + 1) * CLEN) * BATCH + b) * INF, tid, xr);

    // ---- scan across rl lanes (16-lane Hillis-Steele with decay), 2 t-tiles
#pragma unroll
    for (int nt = 0; nt < 4; ++nt)
#pragma unroll
      for (int r = 0; r < 4; ++r) {
        const float la = la2[nt][r];
        // tile 0: inject carry into b0 (lane rl==0): b0 += la*carry
        float v0 = acc[0][nt][r];
        v0 = (rl == 0) ? fmaf(la, carry2[nt][r], v0) : v0;
        float w = la;
#pragma unroll
        for (int d = 1; d <= 8; d <<= 1) {
          float u = __shfl_up(v0, d);
          v0 = (rl >= d) ? fmaf(w, u, v0) : v0;
          w = w * w;
        }
        float c0 = __shfl(v0, seg15);
        // tile 1
        float v1 = acc[1][nt][r];
        v1 = (rl == 0) ? fmaf(la, c0, v1) : v1;
        w = la;
#pragma unroll
        for (int d = 1; d <= 8; d <<= 1) {
          float u = __shfl_up(v1, d);
          v1 = (rl >= d) ? fmaf(w, u, v1) : v1;
          w = w * w;
        }
        carry2[nt][r] = __shfl(v1, seg15);
        acc[0][nt][r] = v0;
        acc[1][nt][r] = v1;
      }

    // ---- bfrag store: lane packs its 4 consecutive n (8B) at row t
    {
      const size_t rowbase = ((size_t)cg * BATCH + b) * 128 + jj * 32;
#pragma unroll
      for (int mt = 0; mt < 2; ++mt)
#pragma unroll
        for (int nt = 0; nt < 4; ++nt) {
          union { bf16 h[4]; unsigned long long u; } pk;
          pk.h[0] = (bf16)acc[mt][nt][0];
          pk.h[1] = (bf16)acc[mt][nt][1];
          pk.h[2] = (bf16)acc[mt][nt][2];
          pk.h[3] = (bf16)acc[mt][nt][3];
          size_t row = rowbase + mt * 16 + rl;
          *(unsigned long long*)(bfrag + row * NST + n0 + nt * 16 + kg * 4) = pk.u;
        }
    }

    if (jj < NJOB - 1) {
      xstore(xs[(jj + 1) & 1], tid, xr);
      __syncthreads();
    } else {
      // group-final state: carry2 holds s[t=31] (valid in all lanes via shfl)
      if (rl == 15)
#pragma unroll
        for (int nt = 0; nt < 4; ++nt) {
          float4 zv = make_float4(carry2[nt][0], carry2[nt][1],
                                  carry2[nt][2], carry2[nt][3]);
          *(float4*)(Z + ((size_t)cg * BATCH + b) * NST + n0 + nt * 16 + kg * 4) = zv;
        }
    }
  }
}

// ---------------------------------------------------------------------------
// K3: exclusive prefix over groups: S0[g] = lamG*S0[g-1] + Z[g-1]; writes fin.
// ---------------------------------------------------------------------------
__global__ __launch_bounds__(128)
void k_chain(const float* __restrict__ Z, const float* __restrict__ lamG,
             float* __restrict__ S0, float* __restrict__ fin) {
  const int b = blockIdx.x;
  const int n = blockIdx.y * 128 + threadIdx.x;
  const float lG = lamG[n];
  float z[NCG];
#pragma unroll
  for (int g = 0; g < NCG; ++g)
    z[g] = Z[((size_t)g * BATCH + b) * NST + n];
  float s = 0.0f;
#pragma unroll
  for (int g = 0; g < NCG; ++g) {
    S0[((size_t)g * BATCH + b) * NST + n] = s;
    s = fmaf(lG, s, z[g]);
  }
  fin[(size_t)b * NST + n] = s;
}

// ---------------------------------------------------------------------------
// GEMM2b: per block = (c2 0..31, b): 64 timestep-rows x 256 o.
// Stage bfrag tile -> LDS with fused carry fixup s = s0 + 2^((dt+1)*log2la)*S0g,
// ONE barrier, then barrier-free K-loop: A from swizzled LDS, C from L2.
// ---------------------------------------------------------------------------
__global__ __launch_bounds__(512)
void k_gemm2b(const bf16* __restrict__ bfrag, const bf16* __restrict__ Cb,
              const float* __restrict__ S0, const float* __restrict__ l2la,
              float* __restrict__ out) {
  __shared__ __align__(16) char ss[64 * NST * 2];   // 64 rows x 1KB, XOR swz

  const int tid = threadIdx.x, wid = tid >> 6, lane = tid & 63;
  const int rl = lane & 15, kg = lane >> 4;
  const int c2 = blockIdx.x >> 5, b = blockIdx.x & 31;
  const int cg = c2 >> 1;
  const int dtbase = (c2 & 1) * 64;

  const int n8 = (tid & 63) * 8;
  float l2a[8], s0g[8];
#pragma unroll
  for (int j = 0; j < 8; ++j) {
    l2a[j] = l2la[n8 + j];
    s0g[j] = S0[((size_t)cg * BATCH + b) * NST + n8 + j];
  }

  const uint4* src = (const uint4*)(bfrag +
      (((size_t)cg * BATCH + b) * 128 + dtbase) * NST);
#pragma unroll
  for (int q = 0; q < 8; ++q) {
    int chunk = q * 512 + tid;
    int tl = chunk >> 6;
    union { uint4 u; bf16 h[8]; } in, ot;
    in.u = src[chunk];
    float dtp1 = (float)(dtbase + tl + 1);
#pragma unroll
    for (int j = 0; j < 8; ++j) {
      float s = fmaf(exp2f(dtp1 * l2a[j]), s0g[j], (float)in.h[j]);
      ot.h[j] = (bf16)s;
    }
    int byte = (tl * (NST * 2) + (chunk & 63) * 16) ^ ((tl & 15) << 4);
    *(uint4*)(&ss[0] + byte) = ot.u;
  }
  __syncthreads();

  const int o0 = wid * 32;
  f32x4 acc[4][2] = {};
#pragma unroll
  for (int kq = 0; kq < 16; ++kq) {
    const int k0 = kq * 32;
    bf16x8 af[4], cf[2];
#pragma unroll
    for (int mf = 0; mf < 4; ++mf) {
      int t = mf * 16 + rl;
      af[mf] = *(const bf16x8*)(&ss[0] +
          ((t * (NST * 2) + (k0 + kg * 8) * 2) ^ ((t & 15) << 4)));
    }
#pragma unroll
    for (int ot2 = 0; ot2 < 2; ++ot2)
      cf[ot2] = *(const bf16x8*)(Cb + (size_t)(o0 + ot2 * 16 + rl) * NST + k0 + kg * 8);
#pragma unroll
    for (int mf = 0; mf < 4; ++mf)
#pragma unroll
      for (int ot2 = 0; ot2 < 2; ++ot2)
        acc[mf][ot2] = __builtin_amdgcn_mfma_f32_16x16x32_bf16(af[mf], cf[ot2], acc[mf][ot2], 0, 0, 0);
  }

#pragma unroll
  for (int mf = 0; mf < 4; ++mf)
#pragma unroll
    for (int ot2 = 0; ot2 < 2; ++ot2)
#pragma unroll
      for (int r = 0; r < 4; ++r) {
        int ml = mf * 16 + kg * 4 + r;
        size_t srow = (size_t)c2 * 64 + ml;
        int o = o0 + ot2 * 16 + rl;
        out[(srow * BATCH + b) * OUTF + o] = acc[mf][ot2][r];
      }
}

// ---------------------------------------------------------------------------
// Fallback: pass0 (old orientation, Z only) + fused pass1 (R5-proven ~142us)
// ---------------------------------------------------------------------------
__global__ __launch_bounds__(512, 2)
void k_pass0_fb(const float* __restrict__ x, const bf16* __restrict__ Bb,
                const float* __restrict__ lam, float* __restrict__ Z) {
  __shared__ __align__(16) char xs[2][CLEN * INF * 2];

  const int tid = threadIdx.x, wid = tid >> 6, lane = tid & 63;
  const int rl = lane & 15, kg = lane >> 4;
  const int b = blockIdx.x >> 4, cg = blockIdx.x & 15;
  const int n0 = wid * 64;

  float la[4], l4[4], carry[4];
#pragma unroll
  for (int nt = 0; nt < 4; ++nt) {
    float v = lam[n0 + nt * 16 + rl];
    la[nt] = v; l4[nt] = (v * v) * (v * v);
    carry[nt] = 0.0f;
  }

  bf16x8 Breg[8][4];
#pragma unroll
  for (int k = 0; k < 8; ++k)
#pragma unroll
    for (int nt = 0; nt < 4; ++nt)
      Breg[k][nt] = *(const bf16x8*)(Bb + (size_t)(n0 + nt * 16 + rl) * INF + k * 32 + kg * 8);

  {
    float4 xr0[4];
    xload(x + ((size_t)(cg * NJOB * CLEN) * BATCH + b) * INF, tid, xr0);
    xstore(xs[0], tid, xr0);
  }
  __syncthreads();

#pragma unroll
  for (int jj = 0; jj < NJOB; ++jj) {
    const int c = cg * NJOB + jj;
    f32x4 acc[2][4] = {};
#pragma unroll
    for (int k = 0; k < 8; ++k) {
      bf16x8 af[2];
#pragma unroll
      for (int mt = 0; mt < 2; ++mt) {
        int row = mt * 16 + rl;
        int byte = (row * (INF * 2) + (k * 32 + kg * 8) * 2) ^ (rl << 4);
        af[mt] = *(const bf16x8*)(&xs[jj & 1][0] + byte);
      }
#pragma unroll
      for (int mt = 0; mt < 2; ++mt)
#pragma unroll
        for (int nt = 0; nt < 4; ++nt)
          acc[mt][nt] = __builtin_amdgcn_mfma_f32_16x16x32_bf16(af[mt], Breg[k][nt], acc[mt][nt], 0, 0, 0);
    }

    if (jj < NJOB - 1) {
      float4 xr[4];
      xload(x + ((size_t)((c + 1) * CLEN) * BATCH + b) * INF, tid, xr);
      reg_scan(acc, carry, la, l4, kg, rl);
      xstore(xs[(jj + 1) & 1], tid, xr);
      __syncthreads();
    } else {
      reg_scan(acc, carry, la, l4, kg, rl);
      if (kg == 0)
#pragma unroll
        for (int nt = 0; nt < 4; ++nt)
          Z[((size_t)cg * BATCH + b) * NST + n0 + nt * 16 + rl] = carry[nt];
    }
  }
}

__global__ __launch_bounds__(512)
void k_pass1_fb(const float* __restrict__ x, const bf16* __restrict__ Bb,
                const bf16* __restrict__ Cb, const float* __restrict__ lam,
                const float* __restrict__ S0, float* __restrict__ out,
                float* __restrict__ fin) {
  __shared__ __align__(16) char xs[2][CLEN * INF * 2];
  __shared__ __align__(16) char ss[CLEN * NST * 2];

  const int tid = threadIdx.x, wid = tid >> 6, lane = tid & 63;
  const int rl = lane & 15, kg = lane >> 4;
  const int b = blockIdx.x >> 4, cg = blockIdx.x & 15;
  const int n0 = wid * 64;

  float la[4], l4[4], carry[4];
#pragma unroll
  for (int nt = 0; nt < 4; ++nt) {
    float v = lam[n0 + nt * 16 + rl];
    la[nt] = v; l4[nt] = (v * v) * (v * v);
    carry[nt] = S0[((size_t)cg * BATCH + b) * NST + n0 + nt * 16 + rl];
  }
  {
    float4 xr0[4];
    xload(x + ((size_t)(cg * NJOB * CLEN) * BATCH + b) * INF, tid, xr0);
    xstore(xs[0], tid, xr0);
  }
  __syncthreads();

#pragma unroll
  for (int jj = 0; jj < NJOB; ++jj) {
    const int c = cg * NJOB + jj;
    f32x4 acc[2][4] = {};
    gemm1_l2(&xs[jj & 1][0], Bb, acc, n0, rl, kg);
    {
      float4 xr[4];
      const int lastj = (jj == NJOB - 1);
      if (!lastj)
        xload(x + ((size_t)((c + 1) * CLEN) * BATCH + b) * INF, tid, xr);
      reg_scan(acc, carry, la, l4, kg, rl);
      if (c == NCH - 1 && kg == 0)
#pragma unroll
        for (int nt = 0; nt < 4; ++nt)
          fin[(size_t)b * NST + n0 + nt * 16 + rl] = carry[nt];
      __syncthreads();
#pragma unroll
      for (int mt = 0; mt < 2; ++mt)
#pragma unroll
        for (int nt = 0; nt < 4; ++nt)
#pragma unroll
          for (int r = 0; r < 4; ++r) {
            int t = mt * 16 + kg * 4 + r;
            int n = n0 + nt * 16 + rl;
            int byte = (t * (NST * 2) + n * 2) ^ ((t & 15) << 4);
            *(bf16*)(&ss[0] + byte) = (bf16)acc[mt][nt][r];
          }
      if (!lastj) xstore(xs[(jj + 1) & 1], tid, xr);
    }
    __syncthreads();

    const int o0 = wid * 32;
    f32x4 a2[2][2] = {};
#pragma unroll
    for (int k0 = 0; k0 < NST; k0 += 32) {
      bf16x8 af[2], cf[2];
#pragma unroll
      for (int mt = 0; mt < 2; ++mt) {
        int t = mt * 16 + rl;
        int byte = (t * (NST * 2) + (k0 + kg * 8) * 2) ^ (rl << 4);
        af[mt] = *(const bf16x8*)(&ss[0] + byte);
      }
#pragma unroll
      for (int ot = 0; ot < 2; ++ot)
        cf[ot] = *(const bf16x8*)(Cb + (size_t)(o0 + ot * 16 + rl) * NST + k0 + kg * 8);
#pragma unroll
      for (int mt = 0; mt < 2; ++mt)
#pragma unroll
        for (int ot = 0; ot < 2; ++ot)
          a2[mt][ot] = __builtin_amdgcn_mfma_f32_16x16x32_bf16(af[mt], cf[ot], a2[mt][ot], 0, 0, 0);
    }
#pragma unroll
    for (int mt = 0; mt < 2; ++mt)
#pragma unroll
      for (int ot = 0; ot < 2; ++ot)
#pragma unroll
        for (int r = 0; r < 4; ++r) {
          int t = mt * 16 + kg * 4 + r;
          int o = o0 + ot * 16 + rl;
          out[(((size_t)(c * CLEN + t)) * BATCH + b) * OUTF + o] = a2[mt][ot][r];
        }
  }
}

// ---------------------------------------------------------------------------
extern "C" void kernel_launch(void* const* d_in, const int* in_sizes, int n_in,
                              void* d_out, int out_size, void* d_ws, size_t ws_size,
                              hipStream_t stream) {
  const float* x  = (const float*)d_in[0];
  const float* ll = (const float*)d_in[1];
  const float* Bm = (const float*)d_in[2];
  const float* Cm = (const float*)d_in[3];

  char* ws = (char*)d_ws;
  float* lam  = (float*)(ws);
  float* lamG = (float*)(ws + 2048);
  float* l2la = (float*)(ws + 4096);
  bf16*  Bb   = (bf16*)(ws + 6144);
  bf16*  Cb   = (bf16*)(ws + 6144 + NST * INF * 2);
  float* Z    = (float*)(ws + 6144 + NST * INF * 2 + OUTF * NST * 2);
  float* S0   = (float*)((char*)Z + (size_t)NCG * BATCH * NST * 4);
  bf16*  bfrag= (bf16*)((char*)S0 + (size_t)NCG * BATCH * NST * 4);
  const size_t NEED = ((char*)bfrag - ws) + (size_t)SEQ * BATCH * NST * 2;  // ~67MB

  float* out = (float*)d_out;
  float* fin = out + (size_t)SEQ * BATCH * OUTF;

  k_prep<<<dim3(512), dim3(256), 0, stream>>>(ll, Bm, Cm, lam, lamG, l2la, Bb, Cb);
  if (ws_size >= NEED) {
    k_pass0s<<<dim3(NBLK), dim3(512), 0, stream>>>(x, Bb, lam, Z, bfrag);
    k_chain<<<dim3(BATCH, 4), dim3(128), 0, stream>>>(Z, lamG, S0, fin);
    k_gemm2b<<<dim3(1024), dim3(512), 0, stream>>>(bfrag, Cb, S0, l2la, out);
  } else {
    k_pass0_fb<<<dim3(NBLK), dim3(512), 0, stream>>>(x, Bb, lam, Z);
    k_chain<<<dim3(BATCH, 4), dim3(128), 0, stream>>>(Z, lamG, S0, fin);
    k_pass1_fb<<<dim3(NBLK), dim3(512), 0, stream>>>(x, Bb, Cb, lam, S0, out, fin);
  }
}

// Round 12
// 98.659 us; speedup vs baseline: 1.8943x; 1.8943x over previous
//
#include <hip/hip_runtime.h>

#define SEQ   2048
#define BATCH 32
#define INF   256
#define NST   512
#define OUTF  256
#define CLEN  32
#define NCH   64
#define NJOB  4
#define NCG   (NCH / NJOB)          /* 16 chunk-groups of 128 timesteps */
#define NBLK  (NCG * BATCH)         /* 512 blocks */

typedef __bf16 bf16;
typedef __bf16 bf16x8 __attribute__((ext_vector_type(8)));
typedef float  f32x4  __attribute__((ext_vector_type(4)));
typedef unsigned long long ull;

// ---------------------------------------------------------------------------
// K1: lam=exp(-exp(ll)); lamG=lam^128; l2la=log2(lam); B'=gamma*B bf16; C bf16
// ---------------------------------------------------------------------------
__global__ void k_prep(const float* __restrict__ ll,
                       const float* __restrict__ Bm,
                       const float* __restrict__ Cm,
                       float* __restrict__ lam,
                       float* __restrict__ lamG,
                       float* __restrict__ l2la,
                       bf16* __restrict__ Bb,
                       bf16* __restrict__ Cb) {
  int i = blockIdx.x * 256 + threadIdx.x;
  if (i < NST) {
    float e = expf(ll[i]);          // -ln(lambda)
    float lmb = expf(-e);
    lam[i] = lmb;
    l2la[i] = -e * 1.44269504088896341f;   // log2(lambda)
    float p = lmb;
#pragma unroll
    for (int q = 0; q < 7; ++q) p *= p;    // lambda^128
    lamG[i] = p;
  }
  if (i < NST * INF) {
    int n = i >> 8;
    float lmb = expf(-expf(ll[n]));
    float g = sqrtf(1.0f - lmb * lmb + 1e-7f);
    Bb[i] = (bf16)(Bm[i] * g);
  }
  if (i < OUTF * NST) {
    Cb[i] = (bf16)(Cm[i]);
  }
}

// ---------------------------------------------------------------------------
// x staging helpers. LDS layout: [t][i] bf16, byte = (t*512+i*2) ^ ((t&15)<<4)
// ---------------------------------------------------------------------------
__device__ __forceinline__ void xload(const float* __restrict__ xp, int tid,
                                      float4 xr[4]) {
#pragma unroll
  for (int rep = 0; rep < 4; ++rep) {
    int slot = rep * 512 + tid;
    int row = slot >> 6, col4 = slot & 63;
    xr[rep] = *(const float4*)(xp + (size_t)row * (BATCH * INF) + col4 * 4);
  }
}

__device__ __forceinline__ void xstore(char* xsb, int tid, const float4 xr[4]) {
#pragma unroll
  for (int rep = 0; rep < 4; ++rep) {
    int slot = rep * 512 + tid;
    int row = slot >> 6, col4 = slot & 63;
    union { bf16 h[4]; ull u; } pk;
    pk.h[0] = (bf16)xr[rep].x; pk.h[1] = (bf16)xr[rep].y;
    pk.h[2] = (bf16)xr[rep].z; pk.h[3] = (bf16)xr[rep].w;
    int byte = (row * (INF * 2) + col4 * 8) ^ ((row & 15) << 4);
    *(ull*)(xsb + byte) = pk.u;
  }
}

// ---------------------------------------------------------------------------
// in-register segmented scan over one chunk (32 t). acc b->s in place.
// ---------------------------------------------------------------------------
__device__ __forceinline__ void reg_scan(f32x4 acc[2][4], float carry[4],
                                         const float la[4], const float l4[4],
                                         int kg, int rl) {
#pragma unroll
  for (int mt = 0; mt < 2; ++mt) {
    float sl[4][4];
#pragma unroll
    for (int nt = 0; nt < 4; ++nt) {
      sl[nt][0] = acc[mt][nt][0];
      sl[nt][1] = fmaf(la[nt], sl[nt][0], acc[mt][nt][1]);
      sl[nt][2] = fmaf(la[nt], sl[nt][1], acc[mt][nt][2]);
      sl[nt][3] = fmaf(la[nt], sl[nt][2], acc[mt][nt][3]);
    }
    float G[4];
#pragma unroll
    for (int nt = 0; nt < 4; ++nt) {
      float g1 = __shfl_up(sl[nt][3], 16);
      G[nt] = (kg >= 1) ? fmaf(l4[nt], g1, sl[nt][3]) : sl[nt][3];
    }
#pragma unroll
    for (int nt = 0; nt < 4; ++nt) {
      float l8 = l4[nt] * l4[nt];
      float g2 = __shfl_up(G[nt], 32);
      G[nt] = (kg >= 2) ? fmaf(l8, g2, G[nt]) : G[nt];
    }
#pragma unroll
    for (int nt = 0; nt < 4; ++nt) {
      float X = __shfl_up(G[nt], 16);
      X = (kg >= 1) ? X : 0.0f;
      float l8 = l4[nt] * l4[nt];
      float p4k = ((kg & 1) ? l4[nt] : 1.0f) * ((kg & 2) ? l8 : 1.0f);
      float cin = fmaf(p4k, carry[nt], X);
      float l2 = la[nt] * la[nt], l3 = l2 * la[nt];
      acc[mt][nt][0] = fmaf(la[nt], cin, sl[nt][0]);
      acc[mt][nt][1] = fmaf(l2, cin, sl[nt][1]);
      acc[mt][nt][2] = fmaf(l3, cin, sl[nt][2]);
      acc[mt][nt][3] = fmaf(l4[nt], cin, sl[nt][3]);
    }
#pragma unroll
    for (int nt = 0; nt < 4; ++nt)
      carry[nt] = __shfl(acc[mt][nt][3], rl + 48);
  }
}

// ---------------------------------------------------------------------------
// GEMM1 with B' streamed from L2 (fallback path only)
// ---------------------------------------------------------------------------
__device__ __forceinline__ void gemm1_l2(const char* xsb, const bf16* __restrict__ Bb,
                                         f32x4 acc[2][4], int n0, int rl, int kg) {
#pragma unroll
  for (int k = 0; k < 8; ++k) {
    bf16x8 af[2], bfr[4];
#pragma unroll
    for (int mt = 0; mt < 2; ++mt) {
      int row = mt * 16 + rl;
      int byte = (row * (INF * 2) + (k * 32 + kg * 8) * 2) ^ (rl << 4);
      af[mt] = *(const bf16x8*)(xsb + byte);
    }
#pragma unroll
    for (int nt = 0; nt < 4; ++nt)
      bfr[nt] = *(const bf16x8*)(Bb + (size_t)(n0 + nt * 16 + rl) * INF + k * 32 + kg * 8);
#pragma unroll
    for (int mt = 0; mt < 2; ++mt)
#pragma unroll
      for (int nt = 0; nt < 4; ++nt)
        acc[mt][nt] = __builtin_amdgcn_mfma_f32_16x16x32_bf16(af[mt], bfr[nt], acc[mt][nt], 0, 0, 0);
  }
}

// ---------------------------------------------------------------------------
// PASS0F: R10 k_pass0<1> structure (Breg, dbuf-x, reg_scan, (512,2)) with
// FRAGMENT-NATIVE bfrag stores: lane packs acc[mt][nt] (4 t at one n) into 8B.
// bfrag index (8B units): ((((cg*32+b)*4+jj)*8+wid)*8 + mt*4+nt)*64 + lane
// ---------------------------------------------------------------------------
__global__ __launch_bounds__(512, 2)
void k_pass0f(const float* __restrict__ x, const bf16* __restrict__ Bb,
              const float* __restrict__ lam, float* __restrict__ Z,
              ull* __restrict__ bfrag) {
  __shared__ __align__(16) char xs[2][CLEN * INF * 2];   // 2x16KB

  const int tid = threadIdx.x, wid = tid >> 6, lane = tid & 63;
  const int rl = lane & 15, kg = lane >> 4;
  const int b = blockIdx.x >> 4, cg = blockIdx.x & 15;
  const int n0 = wid * 64;

  float la[4], l4[4], carry[4];
#pragma unroll
  for (int nt = 0; nt < 4; ++nt) {
    float v = lam[n0 + nt * 16 + rl];
    la[nt] = v; l4[nt] = (v * v) * (v * v);
    carry[nt] = 0.0f;
  }

  bf16x8 Breg[8][4];
#pragma unroll
  for (int k = 0; k < 8; ++k)
#pragma unroll
    for (int nt = 0; nt < 4; ++nt)
      Breg[k][nt] = *(const bf16x8*)(Bb + (size_t)(n0 + nt * 16 + rl) * INF + k * 32 + kg * 8);

  {
    float4 xr0[4];
    xload(x + ((size_t)(cg * NJOB * CLEN) * BATCH + b) * INF, tid, xr0);
    xstore(xs[0], tid, xr0);
  }
  __syncthreads();

#pragma unroll
  for (int jj = 0; jj < NJOB; ++jj) {
    const int c = cg * NJOB + jj;
    f32x4 acc[2][4] = {};
#pragma unroll
    for (int k = 0; k < 8; ++k) {
      bf16x8 af[2];
#pragma unroll
      for (int mt = 0; mt < 2; ++mt) {
        int row = mt * 16 + rl;
        int byte = (row * (INF * 2) + (k * 32 + kg * 8) * 2) ^ (rl << 4);
        af[mt] = *(const bf16x8*)(&xs[jj & 1][0] + byte);
      }
#pragma unroll
      for (int mt = 0; mt < 2; ++mt)
#pragma unroll
        for (int nt = 0; nt < 4; ++nt)
          acc[mt][nt] = __builtin_amdgcn_mfma_f32_16x16x32_bf16(af[mt], Breg[k][nt], acc[mt][nt], 0, 0, 0);
    }

    float4 xr[4];
    if (jj < NJOB - 1)
      xload(x + ((size_t)((c + 1) * CLEN) * BATCH + b) * INF, tid, xr);

    reg_scan(acc, carry, la, l4, kg, rl);

    // fragment-native store: 8 coalesced 8B stores (one per (mt,nt))
    {
      ull* dst = bfrag + ((size_t)(((cg * BATCH + b) * NJOB + jj) * 8 + wid)) * 512 + lane;
#pragma unroll
      for (int mt = 0; mt < 2; ++mt)
#pragma unroll
        for (int nt = 0; nt < 4; ++nt) {
          union { bf16 h[4]; ull u; } pk;
          pk.h[0] = (bf16)acc[mt][nt][0];
          pk.h[1] = (bf16)acc[mt][nt][1];
          pk.h[2] = (bf16)acc[mt][nt][2];
          pk.h[3] = (bf16)acc[mt][nt][3];
          dst[(mt * 4 + nt) * 64] = pk.u;
        }
    }

    if (jj < NJOB - 1) {
      xstore(xs[(jj + 1) & 1], tid, xr);
      __syncthreads();
    } else {
      if (kg == 0)
#pragma unroll
        for (int nt = 0; nt < 4; ++nt)
          Z[((size_t)cg * BATCH + b) * NST + n0 + nt * 16 + rl] = carry[nt];
    }
  }
}

// ---------------------------------------------------------------------------
// K3: exclusive prefix over groups: S0[g] = lamG*S0[g-1] + Z[g-1]; writes fin.
// ---------------------------------------------------------------------------
__global__ __launch_bounds__(128)
void k_chain(const float* __restrict__ Z, const float* __restrict__ lamG,
             float* __restrict__ S0, float* __restrict__ fin) {
  const int b = blockIdx.x;
  const int n = blockIdx.y * 128 + threadIdx.x;
  const float lG = lamG[n];
  float z[NCG];
#pragma unroll
  for (int g = 0; g < NCG; ++g)
    z[g] = Z[((size_t)g * BATCH + b) * NST + n];
  float s = 0.0f;
#pragma unroll
  for (int g = 0; g < NCG; ++g) {
    S0[((size_t)g * BATCH + b) * NST + n] = s;
    s = fmaf(lG, s, z[g]);
  }
  fin[(size_t)b * NST + n] = s;
}

// ---------------------------------------------------------------------------
// GEMM2C: per block = (c2 0..31, b): 64 t-rows x 256 o.
// Stage from FRAGMENT-layout bfrag: decode chunk -> (jj,wid,mt,nt,lane),
// fixup s = s0 + 2^((dt+1)*l2la)*S0g (2 exp2f + iterative), scatter 4x2B
// into swizzled ss[t][n]. Then barrier-free K-loop (A from LDS, C from L2).
// ---------------------------------------------------------------------------
__global__ __launch_bounds__(512)
void k_gemm2c(const ull* __restrict__ bfrag, const bf16* __restrict__ Cb,
              const float* __restrict__ S0, const float* __restrict__ l2la,
              float* __restrict__ out) {
  __shared__ __align__(16) char ss[64 * NST * 2];   // 64 rows x 1KB, XOR swz

  const int tid = threadIdx.x, wid = tid >> 6, lane = tid & 63;
  const int rl = lane & 15, kg = lane >> 4;
  const int c2 = blockIdx.x >> 5, b = blockIdx.x & 31;
  const int cg = c2 >> 1;

  // ---- stage: 8192 8B chunks (2 jobs x 4096), 16 per thread
  const ull* src8 = bfrag +
      ((size_t)((cg * BATCH + b) * NJOB + (c2 & 1) * 2)) * 4096;
  const float* S0g = S0 + ((size_t)cg * BATCH + b) * NST;
#pragma unroll
  for (int q = 0; q < 16; ++q) {
    int chunk = q * 512 + tid;
    int jjh = chunk >> 12;
    int within = chunk & 4095;
    int widx = within >> 9;
    int fr = (within >> 6) & 7;
    int mt = fr >> 2, nt = fr & 3;
    int ls = within & 63;
    int kgs = ls >> 4, rls = ls & 15;
    int n = widx * 64 + nt * 16 + rls;
    int t0 = jjh * 32 + mt * 16 + kgs * 4;         // row within 64-tile
    int dt0 = (c2 & 1) * 64 + t0;                   // row within 128-group

    union { ull u; bf16 h[4]; } in;
    in.u = src8[chunk];
    float l2 = l2la[n];
    float s0 = S0g[n];
    float e = exp2f((float)(dt0 + 1) * l2);         // lambda^(dt0+1)
    float lm = exp2f(l2);                           // lambda
#pragma unroll
    for (int r = 0; r < 4; ++r) {
      float s = fmaf(e, s0, (float)in.h[r]);
      int t = t0 + r;
      int byte = (t * (NST * 2) + n * 2) ^ ((t & 15) << 4);
      *(bf16*)(&ss[0] + byte) = (bf16)s;
      e *= lm;
    }
  }
  __syncthreads();

  // ---- K-loop: wave owns o-panel [wid*32, +32), all 64 rows
  const int o0 = wid * 32;
  f32x4 acc[4][2] = {};
#pragma unroll
  for (int kq = 0; kq < 16; ++kq) {
    const int k0 = kq * 32;
    bf16x8 af[4], cf[2];
#pragma unroll
    for (int mf = 0; mf < 4; ++mf) {
      int t = mf * 16 + rl;
      af[mf] = *(const bf16x8*)(&ss[0] +
          ((t * (NST * 2) + (k0 + kg * 8) * 2) ^ ((t & 15) << 4)));
    }
#pragma unroll
    for (int ot2 = 0; ot2 < 2; ++ot2)
      cf[ot2] = *(const bf16x8*)(Cb + (size_t)(o0 + ot2 * 16 + rl) * NST + k0 + kg * 8);
#pragma unroll
    for (int mf = 0; mf < 4; ++mf)
#pragma unroll
      for (int ot2 = 0; ot2 < 2; ++ot2)
        acc[mf][ot2] = __builtin_amdgcn_mfma_f32_16x16x32_bf16(af[mf], cf[ot2], acc[mf][ot2], 0, 0, 0);
  }

  // ---- epilogue: D row=(lane>>4)*4+reg, col=lane&15
#pragma unroll
  for (int mf = 0; mf < 4; ++mf)
#pragma unroll
    for (int ot2 = 0; ot2 < 2; ++ot2)
#pragma unroll
      for (int r = 0; r < 4; ++r) {
        int ml = mf * 16 + kg * 4 + r;
        size_t srow = (size_t)c2 * 64 + ml;
        int o = o0 + ot2 * 16 + rl;
        out[(srow * BATCH + b) * OUTF + o] = acc[mf][ot2][r];
      }
}

// ---------------------------------------------------------------------------
// Fallback: pass0 (old orientation, Z only) + fused pass1 (R5-proven ~142us)
// ---------------------------------------------------------------------------
__global__ __launch_bounds__(512, 2)
void k_pass0_fb(const float* __restrict__ x, const bf16* __restrict__ Bb,
                const float* __restrict__ lam, float* __restrict__ Z) {
  __shared__ __align__(16) char xs[2][CLEN * INF * 2];

  const int tid = threadIdx.x, wid = tid >> 6, lane = tid & 63;
  const int rl = lane & 15, kg = lane >> 4;
  const int b = blockIdx.x >> 4, cg = blockIdx.x & 15;
  const int n0 = wid * 64;

  float la[4], l4[4], carry[4];
#pragma unroll
  for (int nt = 0; nt < 4; ++nt) {
    float v = lam[n0 + nt * 16 + rl];
    la[nt] = v; l4[nt] = (v * v) * (v * v);
    carry[nt] = 0.0f;
  }

  bf16x8 Breg[8][4];
#pragma unroll
  for (int k = 0; k < 8; ++k)
#pragma unroll
    for (int nt = 0; nt < 4; ++nt)
      Breg[k][nt] = *(const bf16x8*)(Bb + (size_t)(n0 + nt * 16 + rl) * INF + k * 32 + kg * 8);

  {
    float4 xr0[4];
    xload(x + ((size_t)(cg * NJOB * CLEN) * BATCH + b) * INF, tid, xr0);
    xstore(xs[0], tid, xr0);
  }
  __syncthreads();

#pragma unroll
  for (int jj = 0; jj < NJOB; ++jj) {
    const int c = cg * NJOB + jj;
    f32x4 acc[2][4] = {};
#pragma unroll
    for (int k = 0; k < 8; ++k) {
      bf16x8 af[2];
#pragma unroll
      for (int mt = 0; mt < 2; ++mt) {
        int row = mt * 16 + rl;
        int byte = (row * (INF * 2) + (k * 32 + kg * 8) * 2) ^ (rl << 4);
        af[mt] = *(const bf16x8*)(&xs[jj & 1][0] + byte);
      }
#pragma unroll
      for (int mt = 0; mt < 2; ++mt)
#pragma unroll
        for (int nt = 0; nt < 4; ++nt)
          acc[mt][nt] = __builtin_amdgcn_mfma_f32_16x16x32_bf16(af[mt], Breg[k][nt], acc[mt][nt], 0, 0, 0);
    }

    if (jj < NJOB - 1) {
      float4 xr[4];
      xload(x + ((size_t)((c + 1) * CLEN) * BATCH + b) * INF, tid, xr);
      reg_scan(acc, carry, la, l4, kg, rl);
      xstore(xs[(jj + 1) & 1], tid, xr);
      __syncthreads();
    } else {
      reg_scan(acc, carry, la, l4, kg, rl);
      if (kg == 0)
#pragma unroll
        for (int nt = 0; nt < 4; ++nt)
          Z[((size_t)cg * BATCH + b) * NST + n0 + nt * 16 + rl] = carry[nt];
    }
  }
}

__global__ __launch_bounds__(512)
void k_pass1_fb(const float* __restrict__ x, const bf16* __restrict__ Bb,
                const bf16* __restrict__ Cb, const float* __restrict__ lam,
                const float* __restrict__ S0, float* __restrict__ out,
                float* __restrict__ fin) {
  __shared__ __align__(16) char xs[2][CLEN * INF * 2];
  __shared__ __align__(16) char ss[CLEN * NST * 2];

  const int tid = threadIdx.x, wid = tid >> 6, lane = tid & 63;
  const int rl = lane & 15, kg = lane >> 4;
  const int b = blockIdx.x >> 4, cg = blockIdx.x & 15;
  const int n0 = wid * 64;

  float la[4], l4[4], carry[4];
#pragma unroll
  for (int nt = 0; nt < 4; ++nt) {
    float v = lam[n0 + nt * 16 + rl];
    la[nt] = v; l4[nt] = (v * v) * (v * v);
    carry[nt] = S0[((size_t)cg * BATCH + b) * NST + n0 + nt * 16 + rl];
  }
  {
    float4 xr0[4];
    xload(x + ((size_t)(cg * NJOB * CLEN) * BATCH + b) * INF, tid, xr0);
    xstore(xs[0], tid, xr0);
  }
  __syncthreads();

#pragma unroll
  for (int jj = 0; jj < NJOB; ++jj) {
    const int c = cg * NJOB + jj;
    f32x4 acc[2][4] = {};
    gemm1_l2(&xs[jj & 1][0], Bb, acc, n0, rl, kg);
    {
      float4 xr[4];
      const int lastj = (jj == NJOB - 1);
      if (!lastj)
        xload(x + ((size_t)((c + 1) * CLEN) * BATCH + b) * INF, tid, xr);
      reg_scan(acc, carry, la, l4, kg, rl);
      if (c == NCH - 1 && kg == 0)
#pragma unroll
        for (int nt = 0; nt < 4; ++nt)
          fin[(size_t)b * NST + n0 + nt * 16 + rl] = carry[nt];
      __syncthreads();
#pragma unroll
      for (int mt = 0; mt < 2; ++mt)
#pragma unroll
        for (int nt = 0; nt < 4; ++nt)
#pragma unroll
          for (int r = 0; r < 4; ++r) {
            int t = mt * 16 + kg * 4 + r;
            int n = n0 + nt * 16 + rl;
            int byte = (t * (NST * 2) + n * 2) ^ ((t & 15) << 4);
            *(bf16*)(&ss[0] + byte) = (bf16)acc[mt][nt][r];
          }
      if (!lastj) xstore(xs[(jj + 1) & 1], tid, xr);
    }
    __syncthreads();

    const int o0 = wid * 32;
    f32x4 a2[2][2] = {};
#pragma unroll
    for (int k0 = 0; k0 < NST; k0 += 32) {
      bf16x8 af[2], cf[2];
#pragma unroll
      for (int mt = 0; mt < 2; ++mt) {
        int t = mt * 16 + rl;
        int byte = (t * (NST * 2) + (k0 + kg * 8) * 2) ^ (rl << 4);
        af[mt] = *(const bf16x8*)(&ss[0] + byte);
      }
#pragma unroll
      for (int ot = 0; ot < 2; ++ot)
        cf[ot] = *(const bf16x8*)(Cb + (size_t)(o0 + ot * 16 + rl) * NST + k0 + kg * 8);
#pragma unroll
      for (int mt = 0; mt < 2; ++mt)
#pragma unroll
        for (int ot = 0; ot < 2; ++ot)
          a2[mt][ot] = __builtin_amdgcn_mfma_f32_16x16x32_bf16(af[mt], cf[ot], a2[mt][ot], 0, 0, 0);
    }
#pragma unroll
    for (int mt = 0; mt < 2; ++mt)
#pragma unroll
      for (int ot = 0; ot < 2; ++ot)
#pragma unroll
        for (int r = 0; r < 4; ++r) {
          int t = mt * 16 + kg * 4 + r;
          int o = o0 + ot * 16 + rl;
          out[(((size_t)(c * CLEN + t)) * BATCH + b) * OUTF + o] = a2[mt][ot][r];
        }
  }
}

// ---------------------------------------------------------------------------
extern "C" void kernel_launch(void* const* d_in, const int* in_sizes, int n_in,
                              void* d_out, int out_size, void* d_ws, size_t ws_size,
                              hipStream_t stream) {
  const float* x  = (const float*)d_in[0];
  const float* ll = (const float*)d_in[1];
  const float* Bm = (const float*)d_in[2];
  const float* Cm = (const float*)d_in[3];

  char* ws = (char*)d_ws;
  float* lam  = (float*)(ws);
  float* lamG = (float*)(ws + 2048);
  float* l2la = (float*)(ws + 4096);
  bf16*  Bb   = (bf16*)(ws + 6144);
  bf16*  Cb   = (bf16*)(ws + 6144 + NST * INF * 2);
  float* Z    = (float*)(ws + 6144 + NST * INF * 2 + OUTF * NST * 2);
  float* S0   = (float*)((char*)Z + (size_t)NCG * BATCH * NST * 4);
  ull*   bfrag= (ull*)((char*)S0 + (size_t)NCG * BATCH * NST * 4);
  const size_t NEED = ((char*)bfrag - ws) + (size_t)SEQ * BATCH * NST * 2;  // ~67MB

  float* out = (float*)d_out;
  float* fin = out + (size_t)SEQ * BATCH * OUTF;

  k_prep<<<dim3(512), dim3(256), 0, stream>>>(ll, Bm, Cm, lam, lamG, l2la, Bb, Cb);
  if (ws_size >= NEED) {
    k_pass0f<<<dim3(NBLK), dim3(512), 0, stream>>>(x, Bb, lam, Z, bfrag);
    k_chain<<<dim3(BATCH, 4), dim3(128), 0, stream>>>(Z, lamG, S0, fin);
    k_gemm2c<<<dim3(1024), dim3(512), 0, stream>>>(bfrag, Cb, S0, l2la, out);
  } else {
    k_pass0_fb<<<dim3(NBLK), dim3(512), 0, stream>>>(x, Bb, lam, Z);
    k_chain<<<dim3(BATCH, 4), dim3(128), 0, stream>>>(Z, lamG, S0, fin);
    k_pass1_fb<<<dim3(NBLK), dim3(512), 0, stream>>>(x, Bb, Cb, lam, S0, out, fin);
  }
}